// Round 15
// baseline (223.683 us; speedup 1.0000x reference)
//
#include <hip/hip_runtime.h>
#include <hip/hip_fp16.h>
#include <math.h>

#define BB 512   // batch
#define LL 512   // seq len
#define VV 23757 // wd vocab
#define PP 57    // pos vocab
#define NBP 186  // blocks doing P-table work: ceil(((VV+3)/4)*8 / 256)

#define L2E  1.4426950408889634f
#define NL2E (-1.4426950408889634f)
#define TL2E 2.8853900817779268f   // 2*log2(e)

__device__ __forceinline__ float rcp_(float x) { return __builtin_amdgcn_rcpf(x); }
__device__ __forceinline__ float exp2_(float x) { return __builtin_amdgcn_exp2f(x); }
__device__ __forceinline__ float tanh_(float x) { return 1.f - 2.f * rcp_(exp2_(TL2E * x) + 1.f); }

// gate scale: r,z -> -log2e ; n -> 2*log2e   (dg = dir*9 + g*3 + j)
__device__ __forceinline__ float gscale(int dg) {
    int g = (dg % 9) / 3;
    return g == 2 ? TL2E : NL2E;
}
__device__ __forceinline__ int is_rz(int dg) { return ((dg % 9) / 3) < 2; }

// quad_perm broadcast of lane K (0..2) within each 4-lane group, via DPP.
template <int K>
__device__ __forceinline__ float qb(float x) {
    constexpr int ctrl = K * 0x55;
    return __int_as_float(__builtin_amdgcn_update_dpp(0, __float_as_int(x), ctrl, 0xF, 0xF, true));
}

struct H4 { __half2 a, b; };   // 8 bytes: a=(r,z), b=(n,pad)

// conv-folded E entry: E[dg][tt][d] (tap tt reads source position l-2+tt)
__device__ __forceinline__ float e_entry(const float* __restrict__ wd_wih0,
                                         const float* __restrict__ cw2,
                                         const float* __restrict__ cw3,
                                         const float* __restrict__ cw4,
                                         int dg, int tt, int d)
{
    const float* wih = wd_wih0 + dg * 144;
    float acc = 0.f;
    if (tt == 0) {        // offset -2
        for (int o = 0; o < 48; ++o) acc += wih[96 + o] * cw4[o * 400 + d * 4 + 0];
    } else if (tt == 1) { // offset -1
        for (int o = 0; o < 48; ++o) acc += wih[o]      * cw2[o * 200 + d * 2 + 0];
        for (int o = 0; o < 48; ++o) acc += wih[48 + o] * cw3[o * 300 + d * 3 + 0];
        for (int o = 0; o < 48; ++o) acc += wih[96 + o] * cw4[o * 400 + d * 4 + 1];
    } else if (tt == 2) { // offset 0
        for (int o = 0; o < 48; ++o) acc += wih[o]      * cw2[o * 200 + d * 2 + 1];
        for (int o = 0; o < 48; ++o) acc += wih[48 + o] * cw3[o * 300 + d * 3 + 1];
        for (int o = 0; o < 48; ++o) acc += wih[96 + o] * cw4[o * 400 + d * 4 + 2];
    } else {              // offset +1
        for (int o = 0; o < 48; ++o) acc += wih[48 + o] * cw3[o * 300 + d * 3 + 2];
        for (int o = 0; o < 48; ++o) acc += wih[96 + o] * cw4[o * 400 + d * 4 + 3];
    }
    return acc;
}

// ---------------------------------------------------------------------------
// 1. k_prep: blocks [0,NBP) build P16 (computing transposed E into LDS
//    in-kernel); blocks [NBP, NBP+5) build beff (prescaled f32) + Gp (f32).
// ---------------------------------------------------------------------------
__global__ void __launch_bounds__(256) k_prep(
        const float* __restrict__ wd_emb,
        const float* __restrict__ wd_wih0, const float* __restrict__ wd_bih0,
        const float* __restrict__ wd_bhh0,
        const float* __restrict__ cw2, const float* __restrict__ cb2,
        const float* __restrict__ cw3, const float* __restrict__ cb3,
        const float* __restrict__ cw4, const float* __restrict__ cb4,
        const float* __restrict__ pos_emb,
        const float* __restrict__ pos_wih0, const float* __restrict__ pos_bih0,
        const float* __restrict__ pos_bhh0,
        __half* __restrict__ P16, float* __restrict__ beff, float* __restrict__ Gp)
{
    if (blockIdx.x >= NBP) {
        int idx = (blockIdx.x - NBP) * 256 + threadIdx.x;
        if (idx < 18) {
            int dg = idx;
            float acc = wd_bih0[dg];
            for (int o = 0; o < 48; ++o) acc += wd_wih0[dg * 144 + o]      * cb2[o];
            for (int o = 0; o < 48; ++o) acc += wd_wih0[dg * 144 + 48 + o] * cb3[o];
            for (int o = 0; o < 48; ++o) acc += wd_wih0[dg * 144 + 96 + o] * cb4[o];
            if (is_rz(dg)) acc += wd_bhh0[dg];
            beff[dg] = gscale(dg) * acc;
        } else if (idx < 18 + PP * 18) {
            int k = idx - 18;
            int dg = k % 18;
            int p  = k / 18;
            float acc = pos_bih0[dg];
            for (int d = 0; d < 100; ++d) acc += pos_emb[p * 100 + d] * pos_wih0[dg * 100 + d];
            if (is_rz(dg)) acc += pos_bhh0[dg];
            Gp[p * 18 + dg] = gscale(dg) * acc;
        }
        return;
    }

    __shared__ float sEt[7200]; // [d][r], r = tt*18+dg
    for (int i = threadIdx.x; i < 7200; i += 256) {
        int d = i % 100, r = i / 100;
        int tt = r / 18, dg = r % 18;
        sEt[d * 72 + r] = e_entry(wd_wih0, cw2, cw3, cw4, dg, tt, d);
    }
    __syncthreads();
    int T = blockIdx.x * 256 + threadIdx.x;
    int og = T & 7;
    int vb = T >> 3;
    int v0 = vb * 4;
    if (v0 >= VV) return;
    int vlim = VV - 1 - v0;
    float gs[9];
#pragma unroll
    for (int k = 0; k < 9; ++k) {
        int dg = (og * 9 + k) % 18;
        gs[k] = ((dg % 9) / 3 == 2) ? TL2E : NL2E;
    }
    float acc[4][9];
#pragma unroll
    for (int vi = 0; vi < 4; ++vi)
#pragma unroll
        for (int k = 0; k < 9; ++k) acc[vi][k] = 0.f;

    const float* e0 = wd_emb + (size_t)v0 * 100;
#pragma unroll 1
    for (int d4 = 0; d4 < 25; ++d4) {
        float4 ev[4];
#pragma unroll
        for (int vi = 0; vi < 4; ++vi) {
            int vv = vi <= vlim ? vi : vlim;
            ev[vi] = *(const float4*)(e0 + vv * 100 + d4 * 4);
        }
#pragma unroll
        for (int dd = 0; dd < 4; ++dd) {
            int d = d4 * 4 + dd;
            const float* et = sEt + d * 72 + og * 9;
            float em0 = ((const float*)&ev[0])[dd];
            float em1 = ((const float*)&ev[1])[dd];
            float em2 = ((const float*)&ev[2])[dd];
            float em3 = ((const float*)&ev[3])[dd];
#pragma unroll
            for (int k = 0; k < 9; ++k) {
                float e = et[k];
                acc[0][k] = fmaf(em0, e, acc[0][k]);
                acc[1][k] = fmaf(em1, e, acc[1][k]);
                acc[2][k] = fmaf(em2, e, acc[2][k]);
                acc[3][k] = fmaf(em3, e, acc[3][k]);
            }
        }
    }
#pragma unroll
    for (int vi = 0; vi < 4; ++vi) {
        if (vi <= vlim) {
            __half* p = P16 + (size_t)(v0 + vi) * 72 + og * 9;
#pragma unroll
            for (int k = 0; k < 9; ++k) p[k] = __float2half_rn(gs[k] * acc[vi][k]);
        }
    }
}

// ---------------------------------------------------------------------------
// 2. Gather: one thread per (branch,b,l); P fp16, Gp f32.
//    gxh layout [chain][l][j][H4] (24 B/row).
// ---------------------------------------------------------------------------
__global__ void k_gather(const int* __restrict__ wd, const int* __restrict__ pos,
                         const __half* __restrict__ P16, const float* __restrict__ beff,
                         const float* __restrict__ Gp, char* __restrict__ gxh)
{
    int idx = blockIdx.x * blockDim.x + threadIdx.x;
    if (idx >= 2 * BB * LL) return;
    int branch = idx >= BB * LL;
    int k = idx - branch * BB * LL;
    int l = k % LL, b = k / LL;

    float v[18];
    if (!branch) {
#pragma unroll
        for (int i = 0; i < 18; ++i) v[i] = beff[i];
        const int* row = wd + b * LL;
#pragma unroll
        for (int t = 0; t < 4; ++t) {
            int ll = l - 2 + t;
            if (ll >= 0 && ll < LL) {
                const __half2* p = (const __half2*)(P16 + (size_t)row[ll] * 72 + t * 18);
#pragma unroll
                for (int i = 0; i < 9; ++i) {
                    float2 f = __half22float2(p[i]);
                    v[2 * i] += f.x;
                    v[2 * i + 1] += f.y;
                }
            }
        }
    } else {
        const float* p = Gp + pos[k] * 18;
#pragma unroll
        for (int i = 0; i < 18; ++i) v[i] = p[i];
    }
    char* g0 = gxh + ((size_t)((branch * 2 + 0) * BB + b) * LL + l) * 24;
    char* g1 = gxh + ((size_t)((branch * 2 + 1) * BB + b) * LL + l) * 24;
#pragma unroll
    for (int j = 0; j < 3; ++j) {
        H4 w0, w1;
        w0.a = __floats2half2_rn(v[j], v[3 + j]);
        w0.b = __floats2half2_rn(v[6 + j], 0.f);
        w1.a = __floats2half2_rn(v[9 + j], v[12 + j]);
        w1.b = __floats2half2_rn(v[15 + j], 0.f);
        *(H4*)(g0 + j * 8) = w0;
        *(H4*)(g1 + j * 8) = w1;
    }
}

// ---------------------------------------------------------------------------
// Common GRU step (exp2-form, serial FMA). h is the lane's unit state.
// ---------------------------------------------------------------------------
#define GRU_CORE(GR, GZ, GN)                                                  \
    {                                                                         \
        float h0_ = qb<0>(h), h1_ = qb<1>(h), h2_ = qb<2>(h);                 \
        float sr_ = fmaf(wr0, h0_, fmaf(wr1, h1_, fmaf(wr2, h2_, (GR))));     \
        float sz_ = fmaf(wz0, h0_, fmaf(wz1, h1_, fmaf(wz2, h2_, (GZ))));     \
        float g3_ = fmaf(wn0, h0_, fmaf(wn1, h1_, fmaf(wn2, h2_, bnx)));      \
        float r_ = rcp_(1.f + exp2_(sr_));                                    \
        float z_ = rcp_(1.f + exp2_(sz_));                                    \
        float u_ = rcp_(1.f + exp2_(fmaf(r_, g3_, (GN))));                    \
        float n_ = fmaf(-2.f, u_, 1.f);                                       \
        h = fmaf(z_, h - n_, n_);                                             \
    }

// ---------------------------------------------------------------------------
// 3. Scan layer 0. R=32, W=16 -> 48 steps (2 warm + 4 real groups of 8).
//    fp16 streams, named-reg depth-8 prefetch, 2048 blocks, no barriers.
// ---------------------------------------------------------------------------
__global__ void __launch_bounds__(64) k_scan0(
        const char* __restrict__ gxh, char* __restrict__ out0h,
        const float* __restrict__ whhA, const float* __restrict__ bhhA,
        const float* __restrict__ whhB, const float* __restrict__ bhhB)
{
    __shared__ float lbuf[8 * 81];
    int lane = threadIdx.x;
    int c = lane >> 2, sub = lane & 3;   // c = chunk 0..15
    int jj = sub < 3 ? sub : 2;
    int chain = blockIdx.x;
    int branch = chain >> 10;
    int rem = chain & 1023;
    int dir = rem >> 9;

    const float* whh = (branch ? whhB : whhA) + dir * 27;
    const float* bhh = (branch ? bhhB : bhhA) + dir * 9;

    float wr0 = NL2E * whh[jj * 3 + 0], wr1 = NL2E * whh[jj * 3 + 1], wr2 = NL2E * whh[jj * 3 + 2];
    float wz0 = NL2E * whh[(3 + jj) * 3 + 0], wz1 = NL2E * whh[(3 + jj) * 3 + 1], wz2 = NL2E * whh[(3 + jj) * 3 + 2];
    float wn0 = TL2E * whh[(6 + jj) * 3 + 0], wn1 = TL2E * whh[(6 + jj) * 3 + 1], wn2 = TL2E * whh[(6 + jj) * 3 + 2];
    float bnx = TL2E * bhh[6 + jj];

    const int OMAX = 511 * 24;
    int t0 = c * 32 - 16;
    int sstp = dir ? -24 : 24;
    int off = dir ? (OMAX - t0 * 24) : t0 * 24;
    const char* gxc = gxh + (size_t)chain * (LL * 24) + jj * 8;

#define LDP(P) { int a_ = min(max(off, 0), OMAX); P = *(const H4*)(gxc + a_); off += sstp; }
    H4 p0, p1, p2, p3, p4, p5, p6, p7;
    LDP(p0) LDP(p1) LDP(p2) LDP(p3) LDP(p4) LDP(p5) LDP(p6) LDP(p7)

    char* ob = out0h + (size_t)chain * (LL * 8) + sub * 16;
    int wa = c * 5 + sub;

    float h = 0.f;
#define WSTEP(P) { H4 hv_ = P; LDP(P); float2 fa_ = __half22float2(hv_.a); \
                   float fn_ = __half22float2(hv_.b).x; GRU_CORE(fa_.x, fa_.y, fn_) }
#define RSTEP(P, S) { WSTEP(P) lbuf[(S) * 81 + wa] = h; }
#define FLUSH0(TB)                                                            \
    {                                                                         \
        int tbase = (TB);                                                     \
        int l0 = dir ? (LL - 1 - tbase - 7) : tbase;                          \
        _Pragma("unroll")                                                     \
        for (int i = 0; i < 2; ++i) {                                         \
            int lofs = sub * 2 + i;                                           \
            int s = dir ? (7 - lofs) : lofs;                                  \
            H4 hv;                                                            \
            hv.a = __floats2half2_rn(lbuf[s * 81 + c * 5 + 0],                \
                                     lbuf[s * 81 + c * 5 + 1]);               \
            hv.b = __floats2half2_rn(lbuf[s * 81 + c * 5 + 2],                \
                                     lbuf[s * 81 + c * 5 + 3]);               \
            *(H4*)(ob + (size_t)l0 * 8 + i * 8) = hv;                         \
        }                                                                     \
    }

    // ---- warm: 16 steps ----
    for (int g = 0; g < 2; ++g) {
        WSTEP(p0) WSTEP(p1) WSTEP(p2) WSTEP(p3) WSTEP(p4) WSTEP(p5) WSTEP(p6) WSTEP(p7)
    }
    h = c ? h : 0.f;   // chunk 0's real region starts from true h=0

    // ---- real: 32 steps, flush every 8 (1 wave: no barrier) ----
    for (int g = 0; g < 4; ++g) {
        RSTEP(p0, 0) RSTEP(p1, 1) RSTEP(p2, 2) RSTEP(p3, 3)
        RSTEP(p4, 4) RSTEP(p5, 5) RSTEP(p6, 6) RSTEP(p7, 7)
        FLUSH0(t0 + 16 + g * 8)
    }
#undef LDP
#undef WSTEP
#undef RSTEP
#undef FLUSH0
}

// ---------------------------------------------------------------------------
// 4. Scan layer 1, fused input projection (inline-scaled raw weights).
//    R=32, W=16; fp16 in AND out.
// ---------------------------------------------------------------------------
__global__ void __launch_bounds__(64) k_scan1(
        const char* __restrict__ out0h, char* __restrict__ out1h,
        const float* __restrict__ whhA, const float* __restrict__ bhhA,
        const float* __restrict__ whhB, const float* __restrict__ bhhB,
        const float* __restrict__ wihA, const float* __restrict__ bihA,
        const float* __restrict__ wihB, const float* __restrict__ bihB)
{
    __shared__ float lbuf[8 * 81];
    int lane = threadIdx.x;
    int c = lane >> 2, sub = lane & 3;
    int jj = sub < 3 ? sub : 2;
    int chain = blockIdx.x;
    int branch = chain >> 10;
    int rem = chain & 1023;
    int dir = rem >> 9;
    int b = rem & 511;

    const float* whh = (branch ? whhB : whhA) + dir * 27;
    const float* bhh = (branch ? bhhB : bhhA) + dir * 9;

    float wr0 = NL2E * whh[jj * 3 + 0], wr1 = NL2E * whh[jj * 3 + 1], wr2 = NL2E * whh[jj * 3 + 2];
    float wz0 = NL2E * whh[(3 + jj) * 3 + 0], wz1 = NL2E * whh[(3 + jj) * 3 + 1], wz2 = NL2E * whh[(3 + jj) * 3 + 2];
    float wn0 = TL2E * whh[(6 + jj) * 3 + 0], wn1 = TL2E * whh[(6 + jj) * 3 + 1], wn2 = TL2E * whh[(6 + jj) * 3 + 2];
    float bnx = TL2E * bhh[6 + jj];

    const float* wih = branch ? wihB : wihA;
    const float* bih = branch ? bihB : bihA;
    const float* bh1 = branch ? bhhB : bhhA;
    int dgr = dir * 9 + jj, dgz = dgr + 3, dgn = dgr + 6;
    float Wr0 = NL2E * wih[dgr * 6 + 0], Wr1 = NL2E * wih[dgr * 6 + 1], Wr2 = NL2E * wih[dgr * 6 + 2];
    float Wr3 = NL2E * wih[dgr * 6 + 3], Wr4 = NL2E * wih[dgr * 6 + 4], Wr5 = NL2E * wih[dgr * 6 + 5];
    float Wz0 = NL2E * wih[dgz * 6 + 0], Wz1 = NL2E * wih[dgz * 6 + 1], Wz2 = NL2E * wih[dgz * 6 + 2];
    float Wz3 = NL2E * wih[dgz * 6 + 3], Wz4 = NL2E * wih[dgz * 6 + 4], Wz5 = NL2E * wih[dgz * 6 + 5];
    float Wn0 = TL2E * wih[dgn * 6 + 0], Wn1 = TL2E * wih[dgn * 6 + 1], Wn2 = TL2E * wih[dgn * 6 + 2];
    float Wn3 = TL2E * wih[dgn * 6 + 3], Wn4 = TL2E * wih[dgn * 6 + 4], Wn5 = TL2E * wih[dgn * 6 + 5];
    float Br = NL2E * (bih[dgr] + bh1[dgr]);
    float Bz = NL2E * (bih[dgz] + bh1[dgz]);
    float Bn = TL2E * bih[dgn];

    const char* o0c = out0h + (size_t)((branch * 2 + 0) * BB + b) * (LL * 8);
    const char* o1c = out0h + (size_t)((branch * 2 + 1) * BB + b) * (LL * 8);

    const int OMAX = 511 * 8;
    int t0 = c * 32 - 16;
    int sstp = dir ? -8 : 8;
    int off = dir ? (OMAX - t0 * 8) : t0 * 8;

#define LDF(F, Q) { int a_ = min(max(off, 0), OMAX); F = *(const H4*)(o0c + a_); \
                    Q = *(const H4*)(o1c + a_); off += sstp; }
    H4 f0, f1, f2, f3, f4, f5, f6, f7;
    H4 q0, q1, q2, q3, q4, q5, q6, q7;
    LDF(f0, q0) LDF(f1, q1) LDF(f2, q2) LDF(f3, q3)
    LDF(f4, q4) LDF(f5, q5) LDF(f6, q6) LDF(f7, q7)

    char* ob = out1h + (size_t)chain * (LL * 8) + sub * 16;
    int wa = c * 5 + sub;

    float h = 0.f;
#define PRJ_STEP(FV, QV)                                                      \
    {                                                                         \
        float2 fa_ = __half22float2((FV).a);                                  \
        float fn_ = __half22float2((FV).b).x;                                 \
        float2 qa_ = __half22float2((QV).a);                                  \
        float qn_ = __half22float2((QV).b).x;                                 \
        float gr_ = fmaf(fa_.x, Wr0, fmaf(fa_.y, Wr1, fmaf(fn_, Wr2, Br)));   \
        gr_ = fmaf(qa_.x, Wr3, fmaf(qa_.y, Wr4, fmaf(qn_, Wr5, gr_)));        \
        float gz_ = fmaf(fa_.x, Wz0, fmaf(fa_.y, Wz1, fmaf(fn_, Wz2, Bz)));   \
        gz_ = fmaf(qa_.x, Wz3, fmaf(qa_.y, Wz4, fmaf(qn_, Wz5, gz_)));        \
        float gn_ = fmaf(fa_.x, Wn0, fmaf(fa_.y, Wn1, fmaf(fn_, Wn2, Bn)));   \
        gn_ = fmaf(qa_.x, Wn3, fmaf(qa_.y, Wn4, fmaf(qn_, Wn5, gn_)));        \
        GRU_CORE(gr_, gz_, gn_)                                               \
    }
#define WSTEP(F, Q) { H4 fv_ = F, qv_ = Q; LDF(F, Q); PRJ_STEP(fv_, qv_) }
#define RSTEP(F, Q, S) { WSTEP(F, Q) lbuf[(S) * 81 + wa] = h; }
#define FLUSH1(TB)                                                            \
    {                                                                         \
        int tbase = (TB);                                                     \
        int l0 = dir ? (LL - 1 - tbase - 7) : tbase;                          \
        _Pragma("unroll")                                                     \
        for (int i = 0; i < 2; ++i) {                                         \
            int lofs = sub * 2 + i;                                           \
            int s = dir ? (7 - lofs) : lofs;                                  \
            H4 hv;                                                            \
            hv.a = __floats2half2_rn(lbuf[s * 81 + c * 5 + 0],                \
                                     lbuf[s * 81 + c * 5 + 1]);               \
            hv.b = __floats2half2_rn(lbuf[s * 81 + c * 5 + 2],                \
                                     lbuf[s * 81 + c * 5 + 3]);               \
            *(H4*)(ob + (size_t)l0 * 8 + i * 8) = hv;                         \
        }                                                                     \
    }

    // ---- warm: 16 steps ----
    for (int g = 0; g < 2; ++g) {
        WSTEP(f0, q0) WSTEP(f1, q1) WSTEP(f2, q2) WSTEP(f3, q3)
        WSTEP(f4, q4) WSTEP(f5, q5) WSTEP(f6, q6) WSTEP(f7, q7)
    }
    h = c ? h : 0.f;

    // ---- real: 32 steps ----
    for (int g = 0; g < 4; ++g) {
        RSTEP(f0, q0, 0) RSTEP(f1, q1, 1) RSTEP(f2, q2, 2) RSTEP(f3, q3, 3)
        RSTEP(f4, q4, 4) RSTEP(f5, q5, 5) RSTEP(f6, q6, 6) RSTEP(f7, q7, 7)
        FLUSH1(t0 + 16 + g * 8)
    }
#undef LDF
#undef PRJ_STEP
#undef WSTEP
#undef RSTEP
#undef FLUSH1
}

// ---------------------------------------------------------------------------
// 5. Fused head (fp16 out1): attention + posfc/auxi + fc1/fc2 softmax.
// ---------------------------------------------------------------------------
__global__ void k_head(const char* __restrict__ out1h,
                       const float* __restrict__ sw, const float* __restrict__ ap,
                       const float* __restrict__ pg, const float* __restrict__ pb,
                       const float* __restrict__ pw, const float* __restrict__ pbias,
                       const float* __restrict__ f1w, const float* __restrict__ f1b,
                       const float* __restrict__ fg, const float* __restrict__ fb,
                       const float* __restrict__ f2w, const float* __restrict__ f2b,
                       float* __restrict__ out)
{
    int b = blockIdx.x;
    int lane = threadIdx.x;
    __shared__ float ssw[36], sap[6], sph[6], scomb[9], sh[128], sl[6], se[6];
    const float BN = 0.9999950000374997f; // 1/sqrt(1+1e-5)

    if (lane < 36) ssw[lane] = sw[lane];
    if (lane < 6) {
        sap[lane] = ap[lane];
        H4 pf = *(const H4*)(out1h + ((size_t)((2 * BB) + b) * LL + 511) * 8);
        H4 pq = *(const H4*)(out1h + ((size_t)((3 * BB) + b) * LL + 511) * 8);
        float2 fa = __half22float2(pf.a); float fn = __half22float2(pf.b).x;
        float2 ba = __half22float2(pq.a); float bn = __half22float2(pq.b).x;
        float v = lane == 0 ? fa.x : lane == 1 ? fa.y : lane == 2 ? fn
                : lane == 3 ? ba.x : lane == 4 ? ba.y : bn;
        float x = v * BN * pg[lane] + pb[lane];
        sph[lane] = fmaxf(x, 0.f);
    }
    __syncthreads();

    const char* F = out1h + (size_t)b * (LL * 8);
    const char* Bw = out1h + (size_t)(BB + b) * (LL * 8);

    float att[8];
    float mx = -1e30f;
#pragma unroll
    for (int k = 0; k < 8; ++k) {
        int l = lane + 64 * k;
        H4 f4 = *(const H4*)(F + l * 8);
        H4 b4 = *(const H4*)(Bw + l * 8);
        float2 fa = __half22float2(f4.a); float fn = __half22float2(f4.b).x;
        float2 ba = __half22float2(b4.a); float bn = __half22float2(b4.b).x;
        float r0 = fa.x, r1 = fa.y, r2 = fn, r3 = ba.x, r4 = ba.y, r5 = bn;
        float a = 0.f;
#pragma unroll
        for (int j = 0; j < 6; ++j) {
            float s = r0 * ssw[0 * 6 + j] + r1 * ssw[1 * 6 + j] + r2 * ssw[2 * 6 + j] +
                      r3 * ssw[3 * 6 + j] + r4 * ssw[4 * 6 + j] + r5 * ssw[5 * 6 + j];
            a += sap[j] * tanh_(s);
        }
        att[k] = a;
        mx = fmaxf(mx, a);
    }
#pragma unroll
    for (int off = 32; off; off >>= 1) mx = fmaxf(mx, __shfl_xor(mx, off));
    float e[8];
    float sum = 0.f;
#pragma unroll
    for (int k = 0; k < 8; ++k) { e[k] = exp2_(L2E * (att[k] - mx)); sum += e[k]; }
#pragma unroll
    for (int off = 32; off; off >>= 1) sum += __shfl_xor(sum, off);

    float acc[6] = {0.f, 0.f, 0.f, 0.f, 0.f, 0.f};
#pragma unroll
    for (int k = 0; k < 8; ++k) {
        int l = lane + 64 * k;
        H4 f4 = *(const H4*)(F + l * 8);
        H4 b4 = *(const H4*)(Bw + l * 8);
        float2 fa = __half22float2(f4.a); float fn = __half22float2(f4.b).x;
        float2 ba = __half22float2(b4.a); float bn = __half22float2(b4.b).x;
        acc[0] += e[k] * fa.x; acc[1] += e[k] * fa.y; acc[2] += e[k] * fn;
        acc[3] += e[k] * ba.x; acc[4] += e[k] * ba.y; acc[5] += e[k] * bn;
    }
#pragma unroll
    for (int j = 0; j < 6; ++j) {
#pragma unroll
        for (int off = 32; off; off >>= 1) acc[j] += __shfl_xor(acc[j], off);
    }
    if (lane < 6) scomb[lane] = acc[lane] / sum;
    __syncthreads();

    if (lane == 0) {
        float a[3];
#pragma unroll
        for (int j = 0; j < 3; ++j) {
            float t = pbias[j];
#pragma unroll
            for (int i = 0; i < 6; ++i) t += sph[i] * pw[j * 6 + i];
            a[j] = t;
        }
        float m = fmaxf(a[0], fmaxf(a[1], a[2]));
        float e0 = exp2_(L2E * (a[0] - m)), e1 = exp2_(L2E * (a[1] - m)), e2 = exp2_(L2E * (a[2] - m));
        float s = e0 + e1 + e2;
        float x0 = e0 / s, x1 = e1 / s, x2 = e2 / s;
        scomb[6] = x0; scomb[7] = x1; scomb[8] = x2;
        out[BB * 6 + b * 3 + 0] = x0;
        out[BB * 6 + b * 3 + 1] = x1;
        out[BB * 6 + b * 3 + 2] = x2;
    }
    __syncthreads();
    for (int o = lane; o < 128; o += 64) {
        float t = f1b[o];
#pragma unroll
        for (int k = 0; k < 9; ++k) t += scomb[k] * f1w[o * 9 + k];
        float x = t * BN * fg[o] + fb[o];
        sh[o] = fmaxf(x, 0.f);
    }
    __syncthreads();
    if (lane < 6) {
        float t = f2b[lane];
        for (int k = 0; k < 128; ++k) t += sh[k] * f2w[lane * 128 + k];
        sl[lane] = t;
    }
    __syncthreads();
    if (lane < 6) {
        float m = sl[0];
#pragma unroll
        for (int j = 1; j < 6; ++j) m = fmaxf(m, sl[j]);
        se[lane] = exp2_(L2E * (sl[lane] - m));
    }
    __syncthreads();
    if (lane < 6) {
        float s = se[0] + se[1] + se[2] + se[3] + se[4] + se[5];
        out[b * 6 + lane] = se[lane] / s;
    }
}

// ---------------------------------------------------------------------------
extern "C" void kernel_launch(void* const* d_in, const int* in_sizes, int n_in,
                              void* d_out, int out_size, void* d_ws, size_t ws_size,
                              hipStream_t stream)
{
    const int* wd  = (const int*)d_in[0];
    const int* pos = (const int*)d_in[1];
    const float* wd_emb  = (const float*)d_in[2];
    const float* pos_emb = (const float*)d_in[3];
    const float* cw2 = (const float*)d_in[4];  const float* cb2 = (const float*)d_in[5];
    const float* cw3 = (const float*)d_in[6];  const float* cb3 = (const float*)d_in[7];
    const float* cw4 = (const float*)d_in[8];  const float* cb4 = (const float*)d_in[9];
    const float* wd_wih0 = (const float*)d_in[10]; const float* wd_whh0 = (const float*)d_in[11];
    const float* wd_bih0 = (const float*)d_in[12]; const float* wd_bhh0 = (const float*)d_in[13];
    const float* wd_wih1 = (const float*)d_in[14]; const float* wd_whh1 = (const float*)d_in[15];
    const float* wd_bih1 = (const float*)d_in[16]; const float* wd_bhh1 = (const float*)d_in[17];
    const float* pos_wih0 = (const float*)d_in[18]; const float* pos_whh0 = (const float*)d_in[19];
    const float* pos_bih0 = (const float*)d_in[20]; const float* pos_bhh0 = (const float*)d_in[21];
    const float* pos_wih1 = (const float*)d_in[22]; const float* pos_whh1 = (const float*)d_in[23];
    const float* pos_bih1 = (const float*)d_in[24]; const float* pos_bhh1 = (const float*)d_in[25];
    const float* squish_w   = (const float*)d_in[26];
    const float* atten_proj = (const float*)d_in[27];
    const float* posfc_gamma = (const float*)d_in[28]; const float* posfc_beta = (const float*)d_in[29];
    const float* posfc_w = (const float*)d_in[30]; const float* posfc_b = (const float*)d_in[31];
    const float* fc1_w = (const float*)d_in[32]; const float* fc1_b = (const float*)d_in[33];
    const float* fc_gamma = (const float*)d_in[34]; const float* fc_beta = (const float*)d_in[35];
    const float* fc2_w = (const float*)d_in[36]; const float* fc2_b = (const float*)d_in[37];

    float* ws = (float*)d_ws;
    size_t off = 0;
    __half* P16 = (__half*)(ws + off); off += (size_t)VV * 36 + 8;          // fp16 table
    char* out0h = (char*)(ws + off); off += (size_t)4 * BB * LL * 2;        // 8 B/row
    char* out1h = (char*)(ws + off); off += (size_t)4 * BB * LL * 2;        // 8 B/row
    char* gxh = (char*)(ws + off);   off += (size_t)4 * BB * LL * 6;        // 24 B/row
    float* beff = ws + off;   off += 32;
    float* Gp = ws + off;     off += PP * 18 + 14;

    k_prep<<<NBP + 5, 256, 0, stream>>>(
        wd_emb, wd_wih0, wd_bih0, wd_bhh0, cw2, cb2, cw3, cb3, cw4, cb4,
        pos_emb, pos_wih0, pos_bih0, pos_bhh0, P16, beff, Gp);
    k_gather<<<(2 * BB * LL + 255) / 256, 256, 0, stream>>>(wd, pos, P16, beff, Gp, gxh);
    k_scan0<<<2048, 64, 0, stream>>>(gxh, out0h, wd_whh0, wd_bhh0, pos_whh0, pos_bhh0);
    k_scan1<<<2048, 64, 0, stream>>>(out0h, out1h, wd_whh1, wd_bhh1, pos_whh1, pos_bhh1,
                                     wd_wih1, wd_bih1, pos_wih1, pos_bih1);
    k_head<<<BB, 64, 0, stream>>>(out1h, squish_w, atten_proj, posfc_gamma, posfc_beta,
                                  posfc_w, posfc_b, fc1_w, fc1_b, fc_gamma, fc_beta,
                                  fc2_w, fc2_b, (float*)d_out);
}

// Round 16
// 85.302 us; speedup vs baseline: 2.6222x; 2.6222x over previous
//
#include <hip/hip_runtime.h>
#include <hip/hip_fp16.h>
#include <math.h>

#define BB 512   // batch
#define LL 512   // seq len
#define VV 23757 // wd vocab
#define PP 57    // pos vocab

#define L2E  1.4426950408889634f
#define NL2E (-1.4426950408889634f)
#define TL2E 2.8853900817779268f   // 2*log2(e)

__device__ __forceinline__ float rcp_(float x) { return __builtin_amdgcn_rcpf(x); }
__device__ __forceinline__ float exp2_(float x) { return __builtin_amdgcn_exp2f(x); }
__device__ __forceinline__ float tanh_(float x) { return 1.f - 2.f * rcp_(exp2_(TL2E * x) + 1.f); }

// gate scale: r,z -> -log2e ; n -> 2*log2e   (dg = dir*9 + g*3 + j)
__device__ __forceinline__ float gscale(int dg) {
    int g = (dg % 9) / 3;
    return g == 2 ? TL2E : NL2E;
}
__device__ __forceinline__ int is_rz(int dg) { return ((dg % 9) / 3) < 2; }

// quad_perm broadcast of lane K (0..2) within each 4-lane group, via DPP.
template <int K>
__device__ __forceinline__ float qb(float x) {
    constexpr int ctrl = K * 0x55;
    return __int_as_float(__builtin_amdgcn_update_dpp(0, __float_as_int(x), ctrl, 0xF, 0xF, true));
}

struct H4 { __half2 a, b; };   // 8 bytes: a=(r,z), b=(n,pad)

// ---------------------------------------------------------------------------
// 1. Tables (ONCE): E raw [dg][tap][d], beff (prescaled f32), Gp (f32).
// ---------------------------------------------------------------------------
__global__ void k_build_tables(const float* __restrict__ wd_wih0, const float* __restrict__ wd_bih0,
                               const float* __restrict__ wd_bhh0,
                               const float* __restrict__ cw2, const float* __restrict__ cb2,
                               const float* __restrict__ cw3, const float* __restrict__ cb3,
                               const float* __restrict__ cw4, const float* __restrict__ cb4,
                               const float* __restrict__ pos_emb,
                               const float* __restrict__ pos_wih0, const float* __restrict__ pos_bih0,
                               const float* __restrict__ pos_bhh0,
                               float* __restrict__ E, float* __restrict__ beff, float* __restrict__ Gp)
{
    int idx = blockIdx.x * blockDim.x + threadIdx.x;
    if (idx < 7200) {
        int d  = idx % 100;
        int tt = (idx / 100) % 4;
        int dg = idx / 400;
        const float* wih = wd_wih0 + dg * 144;
        float acc = 0.f;
        if (tt == 0) {        // offset -2
            for (int o = 0; o < 48; ++o) acc += wih[96 + o] * cw4[o * 400 + d * 4 + 0];
        } else if (tt == 1) { // offset -1
            for (int o = 0; o < 48; ++o) acc += wih[o]      * cw2[o * 200 + d * 2 + 0];
            for (int o = 0; o < 48; ++o) acc += wih[48 + o] * cw3[o * 300 + d * 3 + 0];
            for (int o = 0; o < 48; ++o) acc += wih[96 + o] * cw4[o * 400 + d * 4 + 1];
        } else if (tt == 2) { // offset 0
            for (int o = 0; o < 48; ++o) acc += wih[o]      * cw2[o * 200 + d * 2 + 1];
            for (int o = 0; o < 48; ++o) acc += wih[48 + o] * cw3[o * 300 + d * 3 + 1];
            for (int o = 0; o < 48; ++o) acc += wih[96 + o] * cw4[o * 400 + d * 4 + 2];
        } else {              // offset +1
            for (int o = 0; o < 48; ++o) acc += wih[48 + o] * cw3[o * 300 + d * 3 + 2];
            for (int o = 0; o < 48; ++o) acc += wih[96 + o] * cw4[o * 400 + d * 4 + 3];
        }
        E[idx] = acc;
    } else if (idx < 7218) {
        int dg = idx - 7200;
        float acc = wd_bih0[dg];
        for (int o = 0; o < 48; ++o) acc += wd_wih0[dg * 144 + o]      * cb2[o];
        for (int o = 0; o < 48; ++o) acc += wd_wih0[dg * 144 + 48 + o] * cb3[o];
        for (int o = 0; o < 48; ++o) acc += wd_wih0[dg * 144 + 96 + o] * cb4[o];
        if (is_rz(dg)) acc += wd_bhh0[dg];
        beff[dg] = gscale(dg) * acc;
    } else if (idx < 8244) {
        int k = idx - 7218;
        int dg = k % 18;
        int p  = k / 18;
        float acc = pos_bih0[dg];
        for (int d = 0; d < 100; ++d) acc += pos_emb[p * 100 + d] * pos_wih0[dg * 100 + d];
        if (is_rz(dg)) acc += pos_bhh0[dg];
        Gp[p * 18 + dg] = gscale(dg) * acc;
    }
}

// ---------------------------------------------------------------------------
// 2. P16[v][tap][dg] = half( s_g * (wd_emb[v,:] . E[dg][tap][:]) )
//    E loaded (not recomputed) into LDS, transposed.
// ---------------------------------------------------------------------------
__global__ void __launch_bounds__(256) k_build_P(const float* __restrict__ wd_emb,
                                                 const float* __restrict__ E,
                                                 __half* __restrict__ P16)
{
    __shared__ float sEt[7200]; // [d][r], r = tt*18+dg
    for (int i = threadIdx.x; i < 7200; i += 256) {
        int d = i % 100, r = i / 100;
        int tt = r / 18, dg = r % 18;
        sEt[d * 72 + r] = E[dg * 400 + tt * 100 + d];
    }
    __syncthreads();
    int T = blockIdx.x * 256 + threadIdx.x;
    int og = T & 7;
    int vb = T >> 3;
    int v0 = vb * 4;
    if (v0 >= VV) return;
    int vlim = VV - 1 - v0;
    float gs[9];
#pragma unroll
    for (int k = 0; k < 9; ++k) {
        int dg = (og * 9 + k) % 18;
        gs[k] = ((dg % 9) / 3 == 2) ? TL2E : NL2E;
    }
    float acc[4][9];
#pragma unroll
    for (int vi = 0; vi < 4; ++vi)
#pragma unroll
        for (int k = 0; k < 9; ++k) acc[vi][k] = 0.f;

    const float* e0 = wd_emb + (size_t)v0 * 100;
#pragma unroll 1
    for (int d4 = 0; d4 < 25; ++d4) {
        float4 ev[4];
#pragma unroll
        for (int vi = 0; vi < 4; ++vi) {
            int vv = vi <= vlim ? vi : vlim;
            ev[vi] = *(const float4*)(e0 + vv * 100 + d4 * 4);
        }
#pragma unroll
        for (int dd = 0; dd < 4; ++dd) {
            int d = d4 * 4 + dd;
            const float* et = sEt + d * 72 + og * 9;
            float em0 = ((const float*)&ev[0])[dd];
            float em1 = ((const float*)&ev[1])[dd];
            float em2 = ((const float*)&ev[2])[dd];
            float em3 = ((const float*)&ev[3])[dd];
#pragma unroll
            for (int k = 0; k < 9; ++k) {
                float e = et[k];
                acc[0][k] = fmaf(em0, e, acc[0][k]);
                acc[1][k] = fmaf(em1, e, acc[1][k]);
                acc[2][k] = fmaf(em2, e, acc[2][k]);
                acc[3][k] = fmaf(em3, e, acc[3][k]);
            }
        }
    }
#pragma unroll
    for (int vi = 0; vi < 4; ++vi) {
        if (vi <= vlim) {
            __half* p = P16 + (size_t)(v0 + vi) * 72 + og * 9;
#pragma unroll
            for (int k = 0; k < 9; ++k) p[k] = __float2half_rn(gs[k] * acc[vi][k]);
        }
    }
}

// ---------------------------------------------------------------------------
// 3. Gather: one thread per (branch,b,l); P fp16, Gp f32.
//    gxh layout [chain][l][j][H4] (24 B/row).
// ---------------------------------------------------------------------------
__global__ void k_gather(const int* __restrict__ wd, const int* __restrict__ pos,
                         const __half* __restrict__ P16, const float* __restrict__ beff,
                         const float* __restrict__ Gp, char* __restrict__ gxh)
{
    int idx = blockIdx.x * blockDim.x + threadIdx.x;
    if (idx >= 2 * BB * LL) return;
    int branch = idx >= BB * LL;
    int k = idx - branch * BB * LL;
    int l = k % LL, b = k / LL;

    float v[18];
    if (!branch) {
#pragma unroll
        for (int i = 0; i < 18; ++i) v[i] = beff[i];
        const int* row = wd + b * LL;
#pragma unroll
        for (int t = 0; t < 4; ++t) {
            int ll = l - 2 + t;
            if (ll >= 0 && ll < LL) {
                const __half2* p = (const __half2*)(P16 + (size_t)row[ll] * 72 + t * 18);
#pragma unroll
                for (int i = 0; i < 9; ++i) {
                    float2 f = __half22float2(p[i]);
                    v[2 * i] += f.x;
                    v[2 * i + 1] += f.y;
                }
            }
        }
    } else {
        const float* p = Gp + pos[k] * 18;
#pragma unroll
        for (int i = 0; i < 18; ++i) v[i] = p[i];
    }
    char* g0 = gxh + ((size_t)((branch * 2 + 0) * BB + b) * LL + l) * 24;
    char* g1 = gxh + ((size_t)((branch * 2 + 1) * BB + b) * LL + l) * 24;
#pragma unroll
    for (int j = 0; j < 3; ++j) {
        H4 w0, w1;
        w0.a = __floats2half2_rn(v[j], v[3 + j]);
        w0.b = __floats2half2_rn(v[6 + j], 0.f);
        w1.a = __floats2half2_rn(v[9 + j], v[12 + j]);
        w1.b = __floats2half2_rn(v[15 + j], 0.f);
        *(H4*)(g0 + j * 8) = w0;
        *(H4*)(g1 + j * 8) = w1;
    }
}

// ---------------------------------------------------------------------------
// Common GRU step (exp2-form, serial FMA). h is the lane's unit state.
// ---------------------------------------------------------------------------
#define GRU_CORE(GR, GZ, GN)                                                  \
    {                                                                         \
        float h0_ = qb<0>(h), h1_ = qb<1>(h), h2_ = qb<2>(h);                 \
        float sr_ = fmaf(wr0, h0_, fmaf(wr1, h1_, fmaf(wr2, h2_, (GR))));     \
        float sz_ = fmaf(wz0, h0_, fmaf(wz1, h1_, fmaf(wz2, h2_, (GZ))));     \
        float g3_ = fmaf(wn0, h0_, fmaf(wn1, h1_, fmaf(wn2, h2_, bnx)));      \
        float r_ = rcp_(1.f + exp2_(sr_));                                    \
        float z_ = rcp_(1.f + exp2_(sz_));                                    \
        float u_ = rcp_(1.f + exp2_(fmaf(r_, g3_, (GN))));                    \
        float n_ = fmaf(-2.f, u_, 1.f);                                       \
        h = fmaf(z_, h - n_, n_);                                             \
    }

// ---------------------------------------------------------------------------
// 4. Scan layer 0. R=32, W=16 -> 48 steps (2 warm + 4 real groups of 8).
//    fp16 streams, named-reg depth-8 prefetch, 2048 blocks, no barriers.
// ---------------------------------------------------------------------------
__global__ void __launch_bounds__(64) k_scan0(
        const char* __restrict__ gxh, char* __restrict__ out0h,
        const float* __restrict__ whhA, const float* __restrict__ bhhA,
        const float* __restrict__ whhB, const float* __restrict__ bhhB)
{
    __shared__ float lbuf[8 * 81];
    int lane = threadIdx.x;
    int c = lane >> 2, sub = lane & 3;   // c = chunk 0..15
    int jj = sub < 3 ? sub : 2;
    int chain = blockIdx.x;
    int branch = chain >> 10;
    int rem = chain & 1023;
    int dir = rem >> 9;

    const float* whh = (branch ? whhB : whhA) + dir * 27;
    const float* bhh = (branch ? bhhB : bhhA) + dir * 9;

    float wr0 = NL2E * whh[jj * 3 + 0], wr1 = NL2E * whh[jj * 3 + 1], wr2 = NL2E * whh[jj * 3 + 2];
    float wz0 = NL2E * whh[(3 + jj) * 3 + 0], wz1 = NL2E * whh[(3 + jj) * 3 + 1], wz2 = NL2E * whh[(3 + jj) * 3 + 2];
    float wn0 = TL2E * whh[(6 + jj) * 3 + 0], wn1 = TL2E * whh[(6 + jj) * 3 + 1], wn2 = TL2E * whh[(6 + jj) * 3 + 2];
    float bnx = TL2E * bhh[6 + jj];

    const int OMAX = 511 * 24;
    int t0 = c * 32 - 16;
    int sstp = dir ? -24 : 24;
    int off = dir ? (OMAX - t0 * 24) : t0 * 24;
    const char* gxc = gxh + (size_t)chain * (LL * 24) + jj * 8;

#define LDP(P) { int a_ = min(max(off, 0), OMAX); P = *(const H4*)(gxc + a_); off += sstp; }
    H4 p0, p1, p2, p3, p4, p5, p6, p7;
    LDP(p0) LDP(p1) LDP(p2) LDP(p3) LDP(p4) LDP(p5) LDP(p6) LDP(p7)

    char* ob = out0h + (size_t)chain * (LL * 8) + sub * 16;
    int wa = c * 5 + sub;

    float h = 0.f;
#define WSTEP(P) { H4 hv_ = P; LDP(P); float2 fa_ = __half22float2(hv_.a); \
                   float fn_ = __half22float2(hv_.b).x; GRU_CORE(fa_.x, fa_.y, fn_) }
#define RSTEP(P, S) { WSTEP(P) lbuf[(S) * 81 + wa] = h; }
#define FLUSH0(TB)                                                            \
    {                                                                         \
        int tbase = (TB);                                                     \
        int l0 = dir ? (LL - 1 - tbase - 7) : tbase;                          \
        _Pragma("unroll")                                                     \
        for (int i = 0; i < 2; ++i) {                                         \
            int lofs = sub * 2 + i;                                           \
            int s = dir ? (7 - lofs) : lofs;                                  \
            H4 hv;                                                            \
            hv.a = __floats2half2_rn(lbuf[s * 81 + c * 5 + 0],                \
                                     lbuf[s * 81 + c * 5 + 1]);               \
            hv.b = __floats2half2_rn(lbuf[s * 81 + c * 5 + 2],                \
                                     lbuf[s * 81 + c * 5 + 3]);               \
            *(H4*)(ob + (size_t)l0 * 8 + i * 8) = hv;                         \
        }                                                                     \
    }

    // ---- warm: 16 steps ----
    for (int g = 0; g < 2; ++g) {
        WSTEP(p0) WSTEP(p1) WSTEP(p2) WSTEP(p3) WSTEP(p4) WSTEP(p5) WSTEP(p6) WSTEP(p7)
    }
    h = c ? h : 0.f;   // chunk 0's real region starts from true h=0

    // ---- real: 32 steps, flush every 8 (1 wave: no barrier) ----
    for (int g = 0; g < 4; ++g) {
        RSTEP(p0, 0) RSTEP(p1, 1) RSTEP(p2, 2) RSTEP(p3, 3)
        RSTEP(p4, 4) RSTEP(p5, 5) RSTEP(p6, 6) RSTEP(p7, 7)
        FLUSH0(t0 + 16 + g * 8)
    }
#undef LDP
#undef WSTEP
#undef RSTEP
#undef FLUSH0
}

// ---------------------------------------------------------------------------
// 5. Scan layer 1, fused input projection (inline-scaled raw weights).
//    R=32, W=16; fp16 in AND out.
// ---------------------------------------------------------------------------
__global__ void __launch_bounds__(64) k_scan1(
        const char* __restrict__ out0h, char* __restrict__ out1h,
        const float* __restrict__ whhA, const float* __restrict__ bhhA,
        const float* __restrict__ whhB, const float* __restrict__ bhhB,
        const float* __restrict__ wihA, const float* __restrict__ bihA,
        const float* __restrict__ wihB, const float* __restrict__ bihB)
{
    __shared__ float lbuf[8 * 81];
    int lane = threadIdx.x;
    int c = lane >> 2, sub = lane & 3;
    int jj = sub < 3 ? sub : 2;
    int chain = blockIdx.x;
    int branch = chain >> 10;
    int rem = chain & 1023;
    int dir = rem >> 9;
    int b = rem & 511;

    const float* whh = (branch ? whhB : whhA) + dir * 27;
    const float* bhh = (branch ? bhhB : bhhA) + dir * 9;

    float wr0 = NL2E * whh[jj * 3 + 0], wr1 = NL2E * whh[jj * 3 + 1], wr2 = NL2E * whh[jj * 3 + 2];
    float wz0 = NL2E * whh[(3 + jj) * 3 + 0], wz1 = NL2E * whh[(3 + jj) * 3 + 1], wz2 = NL2E * whh[(3 + jj) * 3 + 2];
    float wn0 = TL2E * whh[(6 + jj) * 3 + 0], wn1 = TL2E * whh[(6 + jj) * 3 + 1], wn2 = TL2E * whh[(6 + jj) * 3 + 2];
    float bnx = TL2E * bhh[6 + jj];

    const float* wih = branch ? wihB : wihA;
    const float* bih = branch ? bihB : bihA;
    const float* bh1 = branch ? bhhB : bhhA;
    int dgr = dir * 9 + jj, dgz = dgr + 3, dgn = dgr + 6;
    float Wr0 = NL2E * wih[dgr * 6 + 0], Wr1 = NL2E * wih[dgr * 6 + 1], Wr2 = NL2E * wih[dgr * 6 + 2];
    float Wr3 = NL2E * wih[dgr * 6 + 3], Wr4 = NL2E * wih[dgr * 6 + 4], Wr5 = NL2E * wih[dgr * 6 + 5];
    float Wz0 = NL2E * wih[dgz * 6 + 0], Wz1 = NL2E * wih[dgz * 6 + 1], Wz2 = NL2E * wih[dgz * 6 + 2];
    float Wz3 = NL2E * wih[dgz * 6 + 3], Wz4 = NL2E * wih[dgz * 6 + 4], Wz5 = NL2E * wih[dgz * 6 + 5];
    float Wn0 = TL2E * wih[dgn * 6 + 0], Wn1 = TL2E * wih[dgn * 6 + 1], Wn2 = TL2E * wih[dgn * 6 + 2];
    float Wn3 = TL2E * wih[dgn * 6 + 3], Wn4 = TL2E * wih[dgn * 6 + 4], Wn5 = TL2E * wih[dgn * 6 + 5];
    float Br = NL2E * (bih[dgr] + bh1[dgr]);
    float Bz = NL2E * (bih[dgz] + bh1[dgz]);
    float Bn = TL2E * bih[dgn];

    const char* o0c = out0h + (size_t)((branch * 2 + 0) * BB + b) * (LL * 8);
    const char* o1c = out0h + (size_t)((branch * 2 + 1) * BB + b) * (LL * 8);

    const int OMAX = 511 * 8;
    int t0 = c * 32 - 16;
    int sstp = dir ? -8 : 8;
    int off = dir ? (OMAX - t0 * 8) : t0 * 8;

#define LDF(F, Q) { int a_ = min(max(off, 0), OMAX); F = *(const H4*)(o0c + a_); \
                    Q = *(const H4*)(o1c + a_); off += sstp; }
    H4 f0, f1, f2, f3, f4, f5, f6, f7;
    H4 q0, q1, q2, q3, q4, q5, q6, q7;
    LDF(f0, q0) LDF(f1, q1) LDF(f2, q2) LDF(f3, q3)
    LDF(f4, q4) LDF(f5, q5) LDF(f6, q6) LDF(f7, q7)

    char* ob = out1h + (size_t)chain * (LL * 8) + sub * 16;
    int wa = c * 5 + sub;

    float h = 0.f;
#define PRJ_STEP(FV, QV)                                                      \
    {                                                                         \
        float2 fa_ = __half22float2((FV).a);                                  \
        float fn_ = __half22float2((FV).b).x;                                 \
        float2 qa_ = __half22float2((QV).a);                                  \
        float qn_ = __half22float2((QV).b).x;                                 \
        float gr_ = fmaf(fa_.x, Wr0, fmaf(fa_.y, Wr1, fmaf(fn_, Wr2, Br)));   \
        gr_ = fmaf(qa_.x, Wr3, fmaf(qa_.y, Wr4, fmaf(qn_, Wr5, gr_)));        \
        float gz_ = fmaf(fa_.x, Wz0, fmaf(fa_.y, Wz1, fmaf(fn_, Wz2, Bz)));   \
        gz_ = fmaf(qa_.x, Wz3, fmaf(qa_.y, Wz4, fmaf(qn_, Wz5, gz_)));        \
        float gn_ = fmaf(fa_.x, Wn0, fmaf(fa_.y, Wn1, fmaf(fn_, Wn2, Bn)));   \
        gn_ = fmaf(qa_.x, Wn3, fmaf(qa_.y, Wn4, fmaf(qn_, Wn5, gn_)));        \
        GRU_CORE(gr_, gz_, gn_)                                               \
    }
#define WSTEP(F, Q) { H4 fv_ = F, qv_ = Q; LDF(F, Q); PRJ_STEP(fv_, qv_) }
#define RSTEP(F, Q, S) { WSTEP(F, Q) lbuf[(S) * 81 + wa] = h; }
#define FLUSH1(TB)                                                            \
    {                                                                         \
        int tbase = (TB);                                                     \
        int l0 = dir ? (LL - 1 - tbase - 7) : tbase;                          \
        _Pragma("unroll")                                                     \
        for (int i = 0; i < 2; ++i) {                                         \
            int lofs = sub * 2 + i;                                           \
            int s = dir ? (7 - lofs) : lofs;                                  \
            H4 hv;                                                            \
            hv.a = __floats2half2_rn(lbuf[s * 81 + c * 5 + 0],                \
                                     lbuf[s * 81 + c * 5 + 1]);               \
            hv.b = __floats2half2_rn(lbuf[s * 81 + c * 5 + 2],                \
                                     lbuf[s * 81 + c * 5 + 3]);               \
            *(H4*)(ob + (size_t)l0 * 8 + i * 8) = hv;                         \
        }                                                                     \
    }

    // ---- warm: 16 steps ----
    for (int g = 0; g < 2; ++g) {
        WSTEP(f0, q0) WSTEP(f1, q1) WSTEP(f2, q2) WSTEP(f3, q3)
        WSTEP(f4, q4) WSTEP(f5, q5) WSTEP(f6, q6) WSTEP(f7, q7)
    }
    h = c ? h : 0.f;

    // ---- real: 32 steps ----
    for (int g = 0; g < 4; ++g) {
        RSTEP(f0, q0, 0) RSTEP(f1, q1, 1) RSTEP(f2, q2, 2) RSTEP(f3, q3, 3)
        RSTEP(f4, q4, 4) RSTEP(f5, q5, 5) RSTEP(f6, q6, 6) RSTEP(f7, q7, 7)
        FLUSH1(t0 + 16 + g * 8)
    }
#undef LDF
#undef PRJ_STEP
#undef WSTEP
#undef RSTEP
#undef FLUSH1
}

// ---------------------------------------------------------------------------
// 6. Fused head (fp16 out1): attention + posfc/auxi + fc1/fc2 softmax.
// ---------------------------------------------------------------------------
__global__ void k_head(const char* __restrict__ out1h,
                       const float* __restrict__ sw, const float* __restrict__ ap,
                       const float* __restrict__ pg, const float* __restrict__ pb,
                       const float* __restrict__ pw, const float* __restrict__ pbias,
                       const float* __restrict__ f1w, const float* __restrict__ f1b,
                       const float* __restrict__ fg, const float* __restrict__ fb,
                       const float* __restrict__ f2w, const float* __restrict__ f2b,
                       float* __restrict__ out)
{
    int b = blockIdx.x;
    int lane = threadIdx.x;
    __shared__ float ssw[36], sap[6], sph[6], scomb[9], sh[128], sl[6], se[6];
    const float BN = 0.9999950000374997f; // 1/sqrt(1+1e-5)

    if (lane < 36) ssw[lane] = sw[lane];
    if (lane < 6) {
        sap[lane] = ap[lane];
        H4 pf = *(const H4*)(out1h + ((size_t)((2 * BB) + b) * LL + 511) * 8);
        H4 pq = *(const H4*)(out1h + ((size_t)((3 * BB) + b) * LL + 511) * 8);
        float2 fa = __half22float2(pf.a); float fn = __half22float2(pf.b).x;
        float2 ba = __half22float2(pq.a); float bn = __half22float2(pq.b).x;
        float v = lane == 0 ? fa.x : lane == 1 ? fa.y : lane == 2 ? fn
                : lane == 3 ? ba.x : lane == 4 ? ba.y : bn;
        float x = v * BN * pg[lane] + pb[lane];
        sph[lane] = fmaxf(x, 0.f);
    }
    __syncthreads();

    const char* F = out1h + (size_t)b * (LL * 8);
    const char* Bw = out1h + (size_t)(BB + b) * (LL * 8);

    float att[8];
    float mx = -1e30f;
#pragma unroll
    for (int k = 0; k < 8; ++k) {
        int l = lane + 64 * k;
        H4 f4 = *(const H4*)(F + l * 8);
        H4 b4 = *(const H4*)(Bw + l * 8);
        float2 fa = __half22float2(f4.a); float fn = __half22float2(f4.b).x;
        float2 ba = __half22float2(b4.a); float bn = __half22float2(b4.b).x;
        float r0 = fa.x, r1 = fa.y, r2 = fn, r3 = ba.x, r4 = ba.y, r5 = bn;
        float a = 0.f;
#pragma unroll
        for (int j = 0; j < 6; ++j) {
            float s = r0 * ssw[0 * 6 + j] + r1 * ssw[1 * 6 + j] + r2 * ssw[2 * 6 + j] +
                      r3 * ssw[3 * 6 + j] + r4 * ssw[4 * 6 + j] + r5 * ssw[5 * 6 + j];
            a += sap[j] * tanh_(s);
        }
        att[k] = a;
        mx = fmaxf(mx, a);
    }
#pragma unroll
    for (int off = 32; off; off >>= 1) mx = fmaxf(mx, __shfl_xor(mx, off));
    float e[8];
    float sum = 0.f;
#pragma unroll
    for (int k = 0; k < 8; ++k) { e[k] = exp2_(L2E * (att[k] - mx)); sum += e[k]; }
#pragma unroll
    for (int off = 32; off; off >>= 1) sum += __shfl_xor(sum, off);

    float acc[6] = {0.f, 0.f, 0.f, 0.f, 0.f, 0.f};
#pragma unroll
    for (int k = 0; k < 8; ++k) {
        int l = lane + 64 * k;
        H4 f4 = *(const H4*)(F + l * 8);
        H4 b4 = *(const H4*)(Bw + l * 8);
        float2 fa = __half22float2(f4.a); float fn = __half22float2(f4.b).x;
        float2 ba = __half22float2(b4.a); float bn = __half22float2(b4.b).x;
        acc[0] += e[k] * fa.x; acc[1] += e[k] * fa.y; acc[2] += e[k] * fn;
        acc[3] += e[k] * ba.x; acc[4] += e[k] * ba.y; acc[5] += e[k] * bn;
    }
#pragma unroll
    for (int j = 0; j < 6; ++j) {
#pragma unroll
        for (int off = 32; off; off >>= 1) acc[j] += __shfl_xor(acc[j], off);
    }
    if (lane < 6) scomb[lane] = acc[lane] / sum;
    __syncthreads();

    if (lane == 0) {
        float a[3];
#pragma unroll
        for (int j = 0; j < 3; ++j) {
            float t = pbias[j];
#pragma unroll
            for (int i = 0; i < 6; ++i) t += sph[i] * pw[j * 6 + i];
            a[j] = t;
        }
        float m = fmaxf(a[0], fmaxf(a[1], a[2]));
        float e0 = exp2_(L2E * (a[0] - m)), e1 = exp2_(L2E * (a[1] - m)), e2 = exp2_(L2E * (a[2] - m));
        float s = e0 + e1 + e2;
        float x0 = e0 / s, x1 = e1 / s, x2 = e2 / s;
        scomb[6] = x0; scomb[7] = x1; scomb[8] = x2;
        out[BB * 6 + b * 3 + 0] = x0;
        out[BB * 6 + b * 3 + 1] = x1;
        out[BB * 6 + b * 3 + 2] = x2;
    }
    __syncthreads();
    for (int o = lane; o < 128; o += 64) {
        float t = f1b[o];
#pragma unroll
        for (int k = 0; k < 9; ++k) t += scomb[k] * f1w[o * 9 + k];
        float x = t * BN * fg[o] + fb[o];
        sh[o] = fmaxf(x, 0.f);
    }
    __syncthreads();
    if (lane < 6) {
        float t = f2b[lane];
        for (int k = 0; k < 128; ++k) t += sh[k] * f2w[lane * 128 + k];
        sl[lane] = t;
    }
    __syncthreads();
    if (lane < 6) {
        float m = sl[0];
#pragma unroll
        for (int j = 1; j < 6; ++j) m = fmaxf(m, sl[j]);
        se[lane] = exp2_(L2E * (sl[lane] - m));
    }
    __syncthreads();
    if (lane < 6) {
        float s = se[0] + se[1] + se[2] + se[3] + se[4] + se[5];
        out[b * 6 + lane] = se[lane] / s;
    }
}

// ---------------------------------------------------------------------------
extern "C" void kernel_launch(void* const* d_in, const int* in_sizes, int n_in,
                              void* d_out, int out_size, void* d_ws, size_t ws_size,
                              hipStream_t stream)
{
    const int* wd  = (const int*)d_in[0];
    const int* pos = (const int*)d_in[1];
    const float* wd_emb  = (const float*)d_in[2];
    const float* pos_emb = (const float*)d_in[3];
    const float* cw2 = (const float*)d_in[4];  const float* cb2 = (const float*)d_in[5];
    const float* cw3 = (const float*)d_in[6];  const float* cb3 = (const float*)d_in[7];
    const float* cw4 = (const float*)d_in[8];  const float* cb4 = (const float*)d_in[9];
    const float* wd_wih0 = (const float*)d_in[10]; const float* wd_whh0 = (const float*)d_in[11];
    const float* wd_bih0 = (const float*)d_in[12]; const float* wd_bhh0 = (const float*)d_in[13];
    const float* wd_wih1 = (const float*)d_in[14]; const float* wd_whh1 = (const float*)d_in[15];
    const float* wd_bih1 = (const float*)d_in[16]; const float* wd_bhh1 = (const float*)d_in[17];
    const float* pos_wih0 = (const float*)d_in[18]; const float* pos_whh0 = (const float*)d_in[19];
    const float* pos_bih0 = (const float*)d_in[20]; const float* pos_bhh0 = (const float*)d_in[21];
    const float* pos_wih1 = (const float*)d_in[22]; const float* pos_whh1 = (const float*)d_in[23];
    const float* pos_bih1 = (const float*)d_in[24]; const float* pos_bhh1 = (const float*)d_in[25];
    const float* squish_w   = (const float*)d_in[26];
    const float* atten_proj = (const float*)d_in[27];
    const float* posfc_gamma = (const float*)d_in[28]; const float* posfc_beta = (const float*)d_in[29];
    const float* posfc_w = (const float*)d_in[30]; const float* posfc_b = (const float*)d_in[31];
    const float* fc1_w = (const float*)d_in[32]; const float* fc1_b = (const float*)d_in[33];
    const float* fc_gamma = (const float*)d_in[34]; const float* fc_beta = (const float*)d_in[35];
    const float* fc2_w = (const float*)d_in[36]; const float* fc2_b = (const float*)d_in[37];

    float* ws = (float*)d_ws;
    size_t off = 0;
    __half* P16 = (__half*)(ws + off); off += (size_t)VV * 36 + 8;          // fp16 table
    char* out0h = (char*)(ws + off); off += (size_t)4 * BB * LL * 2;        // 8 B/row
    char* out1h = (char*)(ws + off); off += (size_t)4 * BB * LL * 2;        // 8 B/row
    char* gxh = (char*)(ws + off);   off += (size_t)4 * BB * LL * 6;        // 24 B/row
    float* Etab = ws + off;   off += 7200;
    float* beff = ws + off;   off += 32;
    float* Gp = ws + off;     off += PP * 18 + 14;

    k_build_tables<<<(8244 + 255) / 256, 256, 0, stream>>>(
        wd_wih0, wd_bih0, wd_bhh0, cw2, cb2, cw3, cb3, cw4, cb4,
        pos_emb, pos_wih0, pos_bih0, pos_bhh0, Etab, beff, Gp);
    {
        int vb = (VV + 3) / 4;
        int threads = vb * 8;
        k_build_P<<<(threads + 255) / 256, 256, 0, stream>>>(wd_emb, Etab, P16);
    }
    k_gather<<<(2 * BB * LL + 255) / 256, 256, 0, stream>>>(wd, pos, P16, beff, Gp, gxh);
    k_scan0<<<2048, 64, 0, stream>>>(gxh, out0h, wd_whh0, wd_bhh0, pos_whh0, pos_bhh0);
    k_scan1<<<2048, 64, 0, stream>>>(out0h, out1h, wd_whh1, wd_bhh1, pos_whh1, pos_bhh1,
                                     wd_wih1, wd_bih1, pos_wih1, pos_bih1);
    k_head<<<BB, 64, 0, stream>>>(out1h, squish_w, atten_proj, posfc_gamma, posfc_beta,
                                  posfc_w, posfc_b, fc1_w, fc1_b, fc_gamma, fc_beta,
                                  fc2_w, fc2_b, (float*)d_out);
}